// Round 3
// baseline (6519.057 us; speedup 1.0000x reference)
//
#include <hip/hip_runtime.h>

#define T_   256
#define HID_ 1024
#define D2   512

typedef __attribute__((ext_vector_type(8))) short  short8;
typedef __attribute__((ext_vector_type(8))) __bf16 bf16x8;
typedef __attribute__((ext_vector_type(4))) float  f32x4;

__device__ __forceinline__ float sigmoidf_(float x) {
    return __fdividef(1.0f, 1.0f + __expf(-x));
}
__device__ __forceinline__ float tanhf_(float x) {
    return 1.0f - __fdividef(2.0f, 1.0f + __expf(2.0f * x));
}
__device__ __forceinline__ unsigned short bf16hi(float x) {
    unsigned u = __float_as_uint(x);
    return (unsigned short)((u + 0x7FFFu + ((u >> 16) & 1u)) >> 16);
}
__device__ __forceinline__ float bf2f(unsigned short h) {
    return __uint_as_float((unsigned)h << 16);
}
__device__ __forceinline__ f32x4 mfma_(short8 a, short8 b, f32x4 c) {
    union { short8 s; bf16x8 b; } ua, ub;
    ua.s = a; ub.s = b;
    return __builtin_amdgcn_mfma_f32_16x16x32_bf16(ua.b, ub.b, c, 0, 0, 0);
}

// ---- raw asm memory ops (64-bit VGPR address form: works for divergent ptrs)
__device__ __forceinline__ void gl16(short8& d, const void* p) {
    asm volatile("global_load_dwordx4 %0, %1, off" : "=v"(d) : "v"(p));
}
__device__ __forceinline__ void gl16c(short8& d, const void* p) {
    asm volatile("global_load_dwordx4 %0, %1, off sc0 sc1" : "=v"(d) : "v"(p));
}
__device__ __forceinline__ void gs8c(void* p, unsigned long long v) {
    asm volatile("global_store_dwordx2 %0, %1, off sc0 sc1"
                 :: "v"(p), "v"(v) : "memory");
}
#define WAITV0()  asm volatile("s_waitcnt vmcnt(0)" ::: "memory")
#define WAITVN(n) asm volatile("s_waitcnt vmcnt(" #n ")" ::: "memory")
#define SBAR0()   __builtin_amdgcn_sched_barrier(0)
#define ABAR() asm volatile("s_waitcnt lgkmcnt(0)\n\ts_barrier" ::: "memory")

// ---------------- prelim: W2 = fc2_w @ fc1_w, b2 = fc2_w@fc1_b + fc2_b ----
__global__ __launch_bounds__(256) void k_w2(
    const float* __restrict__ fc2_w, const float* __restrict__ fc1_w,
    const float* __restrict__ fc1_b, const float* __restrict__ fc2_b,
    float* __restrict__ W2, float* __restrict__ b2)
{
    int idx = blockIdx.x * 256 + threadIdx.x;   // 0..65535
    int r = idx >> 6, c = idx & 63;
    float acc = 0.f;
    for (int k = 0; k < D2; ++k)
        acc += fc2_w[(size_t)r * D2 + k] * fc1_w[(size_t)k * 64 + c];
    W2[idx] = acc;
    if (c == 0) {
        float a = fc2_b[r];
        for (int k = 0; k < D2; ++k)
            a += fc2_w[(size_t)r * D2 + k] * fc1_b[k];
        b2[r] = a;
    }
}

// -------- prelim: Wc = w_ih @ W2, written in MFMA B-fragment layout --------
// frag idx: ((ct*2 + chunk)*6 + nt)*64 + lane)*8 + e  where lane=quad*16+l15,
// row n = nt*16+l15 -> (gate=n>>5, col=ct*32+(n&31)), K = chunk*32+quad*8+e.
__global__ __launch_bounds__(256) void k_wc(
    const float* __restrict__ w_ih, const float* __restrict__ W2,
    const float* __restrict__ b2, const float* __restrict__ b_ih,
    unsigned short* __restrict__ wc_hi, unsigned short* __restrict__ wc_lo,
    float* __restrict__ bc)
{
    int idx = blockIdx.x * 256 + threadIdx.x;   // 0..196607
    int r = idx >> 6, k = idx & 63;
    float acc = 0.f;
    for (int kk = 0; kk < HID_; ++kk)
        acc += w_ih[(size_t)r * HID_ + kk] * W2[(size_t)kk * 64 + k];
    unsigned short h = bf16hi(acc);
    // scatter to fragment layout
    int gg = r >> 10, col = r & 1023;
    int ct = col >> 5, col32 = col & 31;
    int n = gg * 32 + col32;
    int nt = n >> 4, l15 = n & 15;
    int ch = k >> 5, qd = (k >> 3) & 3, e = k & 7;
    size_t fidx = ((size_t)(((ct * 2 + ch) * 6 + nt) * 64 + qd * 16 + l15)) * 8 + e;
    wc_hi[fidx] = h;
    wc_lo[fidx] = bf16hi(acc - bf2f(h));
    if (k == 0) {
        float a = b_ih[r];
        for (int kk = 0; kk < HID_; ++kk)
            a += w_ih[(size_t)r * HID_ + kk] * b2[kk];
        bc[r] = a;
    }
}

// ------ prelim: w_hh -> bf16 hi/lo planes in MFMA B-fragment layout -------
// out idx = gid*8 where gid = ((ct*32 + c)*6 + nt)*64 + lane; each thread
// gathers its lane-fragment: row R=(n>>5)*1024+ct*32+(n&31), K0=c*32+quad*8.
__global__ __launch_bounds__(256) void k_splitw_f(
    const float* __restrict__ w, unsigned short* __restrict__ hi,
    unsigned short* __restrict__ lo)
{
    int gid = blockIdx.x * 256 + threadIdx.x;   // 0..393215
    int lane = gid & 63;
    int rest = gid >> 6;                        // ct*192 + c*6 + nt
    int nt = rest % 6;
    int cc = (rest / 6) & 31;
    int ct = rest / 192;
    int l15 = lane & 15, quad = lane >> 4;
    int n = nt * 16 + l15;
    int R = (n >> 5) * 1024 + ct * 32 + (n & 31);
    int K0 = cc * 32 + quad * 8;
    const float* src = w + (size_t)R * 1024 + K0;
    float v8[8];
    *(float4*)&v8[0] = *(const float4*)(src);
    *(float4*)&v8[4] = *(const float4*)(src + 4);
    short8 h8, l8;
    #pragma unroll
    for (int i = 0; i < 8; ++i) {
        unsigned short h = bf16hi(v8[i]);
        ((short*)&h8)[i] = (short)h;
        ((short*)&l8)[i] = (short)bf16hi(v8[i] - bf2f(h));
    }
    *(short8*)(hi + (size_t)gid * 8) = h8;
    *(short8*)(lo + (size_t)gid * 8) = l8;
}

// ------- prelim: h0 -> bf16 split planes in fragment-granule layout --------
// layout: byte = (k>>5)*16384 + b*64 + ((k>>3)&3)*16 + (k&7)*2
__global__ __launch_bounds__(256) void k_split_h0(
    const float* __restrict__ hn, unsigned short* __restrict__ hi,
    unsigned short* __restrict__ lo)
{
    int gid = blockIdx.x * 256 + threadIdx.x;      // 0..32767
    int b = gid >> 7, kseg = gid & 127;
    const float* src = hn + (size_t)b * HID_ + kseg * 8;
    short8 h8, l8;
    #pragma unroll
    for (int i = 0; i < 8; ++i) {
        float v = src[i];
        unsigned short h = bf16hi(v);
        ((short*)&h8)[i] = (short)h;
        ((short*)&l8)[i] = (short)bf16hi(v - bf2f(h));
    }
    size_t off = (size_t)(kseg >> 2) * 8192 + b * 32 + (kseg & 3) * 8; // ushorts
    *(short8*)(hi + off) = h8;
    *(short8*)(lo + off) = l8;
}

// ---------------- main persistent GRU kernel (MFMA split-bf16) -------------
// R2 restructure: weights (w_hh, Wc) are pre-arranged in global memory in
// exact per-lane MFMA B-fragment order, so each lane gl16's its fragment
// straight from L2/L1 into registers. The LDS staging ring and its ~30
// s_barriers per step are GONE; LDS is used only for the C-dump/gate phase.
// K-loop: per wave, 16 chunks of {2 A-loads (L3, sc0sc1), 12 B-loads (L2),
// 18 MFMA}, software-pipelined A 3-deep / B 2-deep with counted vmcnt:
//   prologue issues B(c0) B(c1) [pre-spin] then A(c0) A(c1) A(c2);
//   iter i: wait {i0:4, steady:16, i14:14, i15:0}; compute; issue B(c+2),
//   A(c+3). In-order vmcnt retirement forces exactly {A(c),B(c)} each iter.
__global__ __launch_bounds__(256, 1) void k_gru(
    const float* __restrict__ input,
    const float* __restrict__ hn,
    const float* __restrict__ b_hh,
    const float* __restrict__ bc,
    const unsigned short* __restrict__ whh_hi,
    const unsigned short* __restrict__ whh_lo,
    const unsigned short* __restrict__ wc_hi,
    const unsigned short* __restrict__ wc_lo,
    unsigned short* __restrict__ hxA_hi, unsigned short* __restrict__ hxA_lo,
    unsigned short* __restrict__ hxB_hi, unsigned short* __restrict__ hxB_lo,
    float* __restrict__ hn_out,
    int* __restrict__ bar)
{
    const int g = blockIdx.x, ct = g & 31, bt = g >> 5;
    const int j0 = ct << 5, b0 = bt << 5;
    const int tid = threadIdx.x, lane = tid & 63, wid = tid >> 6;
    const int mh = wid & 1, kh = wid >> 1;
    const int l15 = lane & 15, quad = lane >> 4;

    __shared__ float smF[8896];               // C-dump + gate exchange only
    const int SIN_ = 4672, SHN_ = 6784;

    // ---- fragment base pointers (per-lane) ----
    const char* wfh = (const char*)whh_hi + (size_t)ct * 196608 + lane * 16;
    const char* wfl = (const char*)whh_lo + (size_t)ct * 196608 + lane * 16;
    const char* cfh = (const char*)wc_hi + (size_t)(ct * 2 + kh) * 6144 + lane * 16;
    const char* cfl = (const char*)wc_lo + (size_t)(ct * 2 + kh) * 6144 + lane * 16;

    const size_t aoff = (size_t)((b0 + mh * 16 + l15) * 64 + quad * 16);
    const char* aAh = (const char*)hxA_hi + aoff;
    const char* aAl = (const char*)hxA_lo + aoff;
    const char* aBh = (const char*)hxB_hi + aoff;
    const char* aBl = (const char*)hxB_lo + aoff;
    const float* xrow = input + (size_t)(b0 + mh * 16 + l15) * (T_ * 64)
                              + kh * 32 + quad * 8;

    // ---- gate-phase statics: thread owns (b = b0+gb, j = j0+gj4..+3) -----
    const int gb = tid >> 3, gj4 = (tid & 7) << 2;
    float hreg[4], br[4], bz[4], bni[4], bnh[4];
    #pragma unroll
    for (int i = 0; i < 4; ++i) {
        int j = j0 + gj4 + i;
        hreg[i] = hn[(size_t)(b0 + gb) * HID_ + j];
        br[i]  = bc[j] + b_hh[j];
        bz[i]  = bc[1024 + j] + b_hh[1024 + j];
        bni[i] = bc[2048 + j];
        bnh[i] = b_hh[2048 + j];
    }
    const size_t hoff = (size_t)(ct * 16384 + (b0 + gb) * 64 + gj4 * 2);
    char* sAh = (char*)hxA_hi + hoff; char* sAl = (char*)hxA_lo + hoff;
    char* sBh = (char*)hxB_hi + hoff; char* sBl = (char*)hxB_lo + hoff;
    const int g73 = gb * 73, g33 = gb * 33;

    int* arrive  = bar + bt * 128;
    int* release = bar + bt * 128 + 32;

    short8 Bh[2][6], Bl[2][6];   // weight frag banks [chunk parity][nt]
    short8 Ah[3], Al[3];         // A-frag banks (3-deep, hi/lo)
    f32x4 acc[6], acci[2];

#define ISSUE_B(BK, C)                                                        \
  { _Pragma("unroll")                                                         \
    for (int n_ = 0; n_ < 6; ++n_) {                                          \
        gl16(Bh[BK][n_], wfh + (size_t)(C) * 6144 + n_ * 1024);               \
        gl16(Bl[BK][n_], wfl + (size_t)(C) * 6144 + n_ * 1024); } }
#define ISSUE_A(AK, C)                                                        \
  { gl16c(Ah[AK], rh + (size_t)(C) * 16384);                                  \
    gl16c(Al[AK], rl + (size_t)(C) * 16384); }
#define GH_CHUNK(BK, AK)                                                      \
  { _Pragma("unroll")                                                         \
    for (int n_ = 0; n_ < 6; ++n_) {                                          \
        f32x4 v_ = mfma_(Ah[AK], Bh[BK][n_], acc[n_]);                        \
        v_ = mfma_(Ah[AK], Bl[BK][n_], v_);                                   \
        v_ = mfma_(Al[AK], Bh[BK][n_], v_);                                   \
        acc[n_] = v_; } }

    #pragma unroll 1
    for (int t = 0; t < 256; ++t) {
        const char* rh = (t & 1) ? aBh : aAh;   // read planes (h in)
        const char* rl = (t & 1) ? aBl : aAl;
        char* wh = (t & 1) ? sAh : sBh;         // write planes (h out)
        char* wl = (t & 1) ? sAl : sBl;

        // ---- gi phase (h-independent; runs before the inter-block spin) --
        short8 Ch[6], Cl[6];
        #pragma unroll
        for (int n_ = 0; n_ < 6; ++n_) {
            gl16(Ch[n_], cfh + n_ * 1024);
            gl16(Cl[n_], cfl + n_ * 1024);
        }
        float xv[8];
        *(float4*)&xv[0] = *(const float4*)(xrow + (size_t)t * 64);
        *(float4*)&xv[4] = *(const float4*)(xrow + (size_t)t * 64 + 4);
        short8 xa_hi, xa_lo;
        #pragma unroll
        for (int i = 0; i < 8; ++i) {
            unsigned short h = bf16hi(xv[i]);
            ((short*)&xa_hi)[i] = (short)h;
            ((short*)&xa_lo)[i] = (short)bf16hi(xv[i] - bf2f(h));
        }
        WAITV0(); SBAR0();
        #pragma unroll
        for (int n_ = 0; n_ < 6; ++n_) {
            f32x4 z = {0.f, 0.f, 0.f, 0.f};
            f32x4 v = mfma_(xa_hi, Ch[n_], z);
            v = mfma_(xa_hi, Cl[n_], v);
            v = mfma_(xa_lo, Ch[n_], v);
            if (n_ < 4) { acc[n_] = v; }
            else { acci[n_ - 4] = v; acc[n_] = z; }
        }
        // issue w_hh chunks c0,c1 pre-spin (weights are step-invariant)
        ISSUE_B(0, kh);
        ISSUE_B(1, kh + 2);
        // ---- wait for h(t) published ----
        if (t > 0 && tid == 0) {
            while (__hip_atomic_load(release, __ATOMIC_RELAXED,
                                     __HIP_MEMORY_SCOPE_SYSTEM) < t)
                __builtin_amdgcn_s_sleep(4);
        }
        ABAR();
        // ---- A prologue: 3 banks deep ----
        ISSUE_A(0, kh);
        ISSUE_A(1, kh + 2);
        ISSUE_A(2, kh + 4);
        // ---- K-loop: 16 chunks, no barriers, counted vmcnt pipeline ----
        #pragma unroll
        for (int i = 0; i < 16; ++i) {
            if (i == 0)       { WAITVN(4);  }
            else if (i == 14) { WAITVN(14); }
            else if (i == 15) { WAITVN(0);  }
            else              { WAITVN(16); }
            SBAR0();
            GH_CHUNK(i & 1, i % 3);
            if (i < 14) ISSUE_B(i & 1, kh + 2 * i + 4);
            if (i < 13) ISSUE_A(i % 3, kh + 2 * i + 6);
        }
        // ---- dump C fragments ----
        {
            const int row = mh * 16 + quad * 4;
            #pragma unroll
            for (int nt = 0; nt < 4; ++nt)
                #pragma unroll
                for (int r = 0; r < 4; ++r)
                    smF[kh * 2336 + (row + r) * 73 + nt * 16 + l15] = acc[nt][r];
            #pragma unroll
            for (int jn = 0; jn < 2; ++jn)
                #pragma unroll
                for (int r = 0; r < 4; ++r) {
                    smF[SHN_ + kh * 1056 + (row + r) * 33 + jn * 16 + l15] = acc[4 + jn][r];
                    smF[SIN_ + kh * 1056 + (row + r) * 33 + jn * 16 + l15] = acci[jn][r];
                }
        }
        __syncthreads();
        // ---- gate phase: thread owns (gb, gj4..+3); hprev in registers ----
        unsigned short ph4[4], pl4[4];
        #pragma unroll
        for (int i = 0; i < 4; ++i) {
            int cl = gj4 + i;
            float rp = smF[g73 + cl] + smF[2336 + g73 + cl] + br[i];
            float zp = smF[g73 + 32 + cl] + smF[2336 + g73 + 32 + cl] + bz[i];
            float ip = smF[SIN_ + g33 + cl] + smF[SIN_ + 1056 + g33 + cl] + bni[i];
            float hp = smF[SHN_ + g33 + cl] + smF[SHN_ + 1056 + g33 + cl] + bnh[i];
            float rr = sigmoidf_(rp);
            float zz = sigmoidf_(zp);
            float nn = tanhf_(ip + rr * hp);
            float hv = (1.0f - zz) * nn + zz * hreg[i];
            hreg[i] = hv;
            unsigned short hh = bf16hi(hv);
            ph4[i] = hh;
            pl4[i] = bf16hi(hv - bf2f(hh));
        }
        unsigned long long pk_hi =
            (unsigned long long)ph4[0] | ((unsigned long long)ph4[1] << 16) |
            ((unsigned long long)ph4[2] << 32) | ((unsigned long long)ph4[3] << 48);
        unsigned long long pk_lo =
            (unsigned long long)pl4[0] | ((unsigned long long)pl4[1] << 16) |
            ((unsigned long long)pl4[2] << 32) | ((unsigned long long)pl4[3] << 48);
        gs8c(wh, pk_hi);
        gs8c(wl, pk_lo);
        if (t == 255) {
            #pragma unroll
            for (int i = 0; i < 4; ++i)
                hn_out[(size_t)(b0 + gb) * HID_ + j0 + gj4 + i] = hreg[i];
        }
        WAITV0();           // h-plane stores at coherence point
        __syncthreads();    // whole block done
        if (t < 255 && tid == 0) {
            int old = __hip_atomic_fetch_add(arrive, 1, __ATOMIC_RELAXED,
                                             __HIP_MEMORY_SCOPE_SYSTEM);
            if (old == ((t + 1) << 5) - 1)
                __hip_atomic_store(release, t + 1, __ATOMIC_RELAXED,
                                   __HIP_MEMORY_SCOPE_SYSTEM);
        }
    }
#undef GH_CHUNK
#undef ISSUE_A
#undef ISSUE_B
}

// ---------------- fc3: out3 = relu(relu(h) @ fc3_wT + fc3_b) --------------
__global__ __launch_bounds__(256) void k_fc3(
    const float* __restrict__ h, const float* __restrict__ fc3_w,
    const float* __restrict__ fc3_b, float* __restrict__ out3)
{
    const int bt = blockIdx.x >> 3;
    const int dt = blockIdx.x & 7;
    const int b0 = bt << 6;
    const int d0 = dt << 6;
    const int tid = threadIdx.x;
    const int tx = tid & 15, ty = tid >> 4;

    __shared__ float sh_h[64][36];
    __shared__ float sh_w[64][36];

    float acc[4][4] = {};
    const int lr = tid >> 3;
    const int lc = (tid & 7) << 2;

    for (int kk = 0; kk < HID_; kk += 32) {
        #pragma unroll
        for (int p = 0; p < 2; ++p) {
            int row = lr + (p << 5);
            float4 v = *(const float4*)(h + (size_t)(b0 + row) * HID_ + kk + lc);
            v.x = fmaxf(v.x, 0.f); v.y = fmaxf(v.y, 0.f);
            v.z = fmaxf(v.z, 0.f); v.w = fmaxf(v.w, 0.f);
            *(float4*)&sh_h[row][lc] = v;
            *(float4*)&sh_w[row][lc] =
                *(const float4*)(fc3_w + (size_t)(d0 + row) * HID_ + kk + lc);
        }
        __syncthreads();
        #pragma unroll
        for (int k = 0; k < 32; ++k) {
            float hv[4], wv[4];
            #pragma unroll
            for (int i = 0; i < 4; ++i) hv[i] = sh_h[ty + (i << 4)][k];
            #pragma unroll
            for (int q = 0; q < 4; ++q) wv[q] = sh_w[tx + (q << 4)][k];
            #pragma unroll
            for (int i = 0; i < 4; ++i)
                #pragma unroll
                for (int q = 0; q < 4; ++q)
                    acc[i][q] += hv[i] * wv[q];
        }
        __syncthreads();
    }
    #pragma unroll
    for (int i = 0; i < 4; ++i) {
        int b = b0 + ty + (i << 4);
        #pragma unroll
        for (int q = 0; q < 4; ++q) {
            int d = d0 + tx + (q << 4);
            out3[(size_t)b * D2 + d] = fmaxf(acc[i][q] + fc3_b[d], 0.f);
        }
    }
}

// ---------------- heads: params[b,o] = out3[b,:]·heads_w[cid[b],o,:]+b ----
__global__ __launch_bounds__(256) void k_heads(
    const float* __restrict__ out3, const int* __restrict__ cult,
    const float* __restrict__ hw, const float* __restrict__ hb,
    float* __restrict__ params)
{
    int b = blockIdx.x;
    int o = threadIdx.x >> 4;
    int l = threadIdx.x & 15;
    int cid = cult[b];
    const float* w = hw + ((size_t)cid * 16 + o) * D2;
    const float* x = out3 + (size_t)b * D2;
    float acc = 0.f;
    #pragma unroll
    for (int m = 0; m < 8; ++m) {
        int d4 = (l + (m << 4)) << 2;
        float4 xv = *(const float4*)(x + d4);
        float4 wv = *(const float4*)(w + d4);
        acc += xv.x * wv.x + xv.y * wv.y + xv.z * wv.z + xv.w * wv.w;
    }
    #pragma unroll
    for (int s = 1; s < 16; s <<= 1)
        acc += __shfl_xor(acc, s, 16);
    if (l == 0)
        params[(size_t)b * 16 + o] = acc + hb[(size_t)cid * 16 + o];
}

extern "C" void kernel_launch(void* const* d_in, const int* in_sizes, int n_in,
                              void* d_out, int out_size, void* d_ws, size_t ws_size,
                              hipStream_t stream)
{
    const float* input = (const float*)d_in[0];
    const float* hn    = (const float*)d_in[1];
    const int*   cult  = (const int*)d_in[2];
    const float* fc1_w = (const float*)d_in[3];
    const float* fc1_b = (const float*)d_in[4];
    const float* fc2_w = (const float*)d_in[5];
    const float* fc2_b = (const float*)d_in[6];
    const float* w_ih  = (const float*)d_in[7];
    const float* w_hh  = (const float*)d_in[8];
    const float* b_ih  = (const float*)d_in[9];
    const float* b_hh  = (const float*)d_in[10];
    const float* fc3_w = (const float*)d_in[11];
    const float* fc3_b = (const float*)d_in[12];
    const float* hw    = (const float*)d_in[13];
    const float* hb    = (const float*)d_in[14];
    float* out = (float*)d_out;
    float* hn_out = out + 4096;          // params 256*16, then hn 256*1024

    char* ws = (char*)d_ws;
    int*   bar    = (int*)ws;                                   // 4 KB
    float* W2     = (float*)(ws + 4096);                        // 256 KB
    float* b2     = (float*)(ws + 266240);
    float* bc     = (float*)(ws + 270336);
    unsigned short* whh_hi = (unsigned short*)(ws + 282624);    // 6 MB
    unsigned short* whh_lo = (unsigned short*)(ws + 282624 + 6291456);
    unsigned short* wc_hi  = (unsigned short*)(ws + 12865536);
    unsigned short* wc_lo  = (unsigned short*)(ws + 13258752);
    unsigned short* hxA_hi = (unsigned short*)(ws + 13651968);
    unsigned short* hxA_lo = (unsigned short*)(ws + 14176256);
    unsigned short* hxB_hi = (unsigned short*)(ws + 14700544);
    unsigned short* hxB_lo = (unsigned short*)(ws + 15224832);
    float* out3   = (float*)(ws + 15749120);                    // 512 KB

    hipMemsetAsync(bar, 0, 4096, stream);
    k_w2<<<256, 256, 0, stream>>>(fc2_w, fc1_w, fc1_b, fc2_b, W2, b2);
    k_wc<<<768, 256, 0, stream>>>(w_ih, W2, b2, b_ih, wc_hi, wc_lo, bc);
    k_splitw_f<<<1536, 256, 0, stream>>>(w_hh, whh_hi, whh_lo);
    k_split_h0<<<128, 256, 0, stream>>>(hn, hxA_hi, hxA_lo);
    k_gru<<<256, 256, 0, stream>>>(input, hn, b_hh, bc,
                                   whh_hi, whh_lo, wc_hi, wc_lo,
                                   hxA_hi, hxA_lo, hxB_hi, hxB_lo,
                                   hn_out, bar);
    k_fc3<<<32, 256, 0, stream>>>(hn_out, fc3_w, fc3_b, out3);
    k_heads<<<256, 256, 0, stream>>>(out3, cult, hw, hb, out);
}

// Round 5
// 4412.758 us; speedup vs baseline: 1.4773x; 1.4773x over previous
//
#include <hip/hip_runtime.h>

#define T_   256
#define HID_ 1024
#define D2   512

typedef __attribute__((ext_vector_type(8))) short  short8;
typedef __attribute__((ext_vector_type(8))) __bf16 bf16x8;
typedef __attribute__((ext_vector_type(4))) float  f32x4;

__device__ __forceinline__ float sigmoidf_(float x) {
    return __fdividef(1.0f, 1.0f + __expf(-x));
}
__device__ __forceinline__ float tanhf_(float x) {
    return 1.0f - __fdividef(2.0f, 1.0f + __expf(2.0f * x));
}
__device__ __forceinline__ unsigned short bf16hi(float x) {
    unsigned u = __float_as_uint(x);
    return (unsigned short)((u + 0x7FFFu + ((u >> 16) & 1u)) >> 16);
}
__device__ __forceinline__ float bf2f(unsigned short h) {
    return __uint_as_float((unsigned)h << 16);
}
__device__ __forceinline__ f32x4 mfma_(short8 a, short8 b, f32x4 c) {
    union { short8 s; bf16x8 b; } ua, ub;
    ua.s = a; ub.s = b;
    return __builtin_amdgcn_mfma_f32_16x16x32_bf16(ua.b, ub.b, c, 0, 0, 0);
}

// ---- raw asm memory ops (64-bit VGPR address form: works for divergent ptrs)
__device__ __forceinline__ void gl16(short8& d, const void* p) {
    asm volatile("global_load_dwordx4 %0, %1, off" : "=v"(d) : "v"(p));
}
__device__ __forceinline__ void gl16c(short8& d, const void* p) {
    asm volatile("global_load_dwordx4 %0, %1, off sc0 sc1" : "=v"(d) : "v"(p));
}
__device__ __forceinline__ void gs8c(void* p, unsigned long long v) {
    asm volatile("global_store_dwordx2 %0, %1, off sc0 sc1"
                 :: "v"(p), "v"(v) : "memory");
}
#define WAITV0() asm volatile("s_waitcnt vmcnt(0)" ::: "memory")
#define WAITV2() asm volatile("s_waitcnt vmcnt(2)" ::: "memory")
// vmcnt(5) keeps the newest {3x w-loads, 2x A-loads} in flight (R1 scheme).
#define WAITV5_TIE(H, L) asm volatile("s_waitcnt vmcnt(5)" : "+v"(H), "+v"(L) :: "memory")
#define WAITV0_TIE(H, L) asm volatile("s_waitcnt vmcnt(0)" : "+v"(H), "+v"(L) :: "memory")
#define ABAR() asm volatile("s_waitcnt lgkmcnt(0)\n\ts_barrier" ::: "memory")

// ---------------- prelim: W2 = fc2_w @ fc1_w, b2 = fc2_w@fc1_b + fc2_b ----
__global__ __launch_bounds__(256) void k_w2(
    const float* __restrict__ fc2_w, const float* __restrict__ fc1_w,
    const float* __restrict__ fc1_b, const float* __restrict__ fc2_b,
    float* __restrict__ W2, float* __restrict__ b2)
{
    int idx = blockIdx.x * 256 + threadIdx.x;   // 0..65535
    int r = idx >> 6, c = idx & 63;
    float acc = 0.f;
    for (int k = 0; k < D2; ++k)
        acc += fc2_w[(size_t)r * D2 + k] * fc1_w[(size_t)k * 64 + c];
    W2[idx] = acc;
    if (c == 0) {
        float a = fc2_b[r];
        for (int k = 0; k < D2; ++k)
            a += fc2_w[(size_t)r * D2 + k] * fc1_b[k];
        b2[r] = a;
    }
}

// -------- prelim: Wc = w_ih @ W2 (bf16 split planes), bc = w_ih@b2 + b_ih --
__global__ __launch_bounds__(256) void k_wc(
    const float* __restrict__ w_ih, const float* __restrict__ W2,
    const float* __restrict__ b2, const float* __restrict__ b_ih,
    unsigned short* __restrict__ wc_hi, unsigned short* __restrict__ wc_lo,
    float* __restrict__ bc)
{
    int idx = blockIdx.x * 256 + threadIdx.x;   // 0..196607
    int r = idx >> 6, c = idx & 63;
    float acc = 0.f;
    for (int k = 0; k < HID_; ++k)
        acc += w_ih[(size_t)r * HID_ + k] * W2[(size_t)k * 64 + c];
    unsigned short h = bf16hi(acc);
    wc_hi[idx] = h;
    wc_lo[idx] = bf16hi(acc - bf2f(h));
    if (c == 0) {
        float a = b_ih[r];
        for (int k = 0; k < HID_; ++k)
            a += w_ih[(size_t)r * HID_ + k] * b2[k];
        bc[r] = a;
    }
}

// ---------------- prelim: split w_hh into bf16 hi/lo planes ----------------
__global__ __launch_bounds__(256) void k_splitw(
    const float* __restrict__ w, unsigned short* __restrict__ hi,
    unsigned short* __restrict__ lo)
{
    int i4 = (blockIdx.x * 256 + threadIdx.x) * 4;
    float4 v = *(const float4*)(w + i4);
    float vv[4] = {v.x, v.y, v.z, v.w};
    unsigned short h4[4], l4[4];
    #pragma unroll
    for (int i = 0; i < 4; ++i) {
        h4[i] = bf16hi(vv[i]);
        l4[i] = bf16hi(vv[i] - bf2f(h4[i]));
    }
    *(unsigned long long*)(hi + i4) =
        (unsigned long long)h4[0] | ((unsigned long long)h4[1] << 16) |
        ((unsigned long long)h4[2] << 32) | ((unsigned long long)h4[3] << 48);
    *(unsigned long long*)(lo + i4) =
        (unsigned long long)l4[0] | ((unsigned long long)l4[1] << 16) |
        ((unsigned long long)l4[2] << 32) | ((unsigned long long)l4[3] << 48);
}

// ------- prelim: h0 -> bf16 split planes in fragment-granule layout --------
// layout: byte = (k>>5)*16384 + b*64 + ((k>>3)&3)*16 + (k&7)*2
__global__ __launch_bounds__(256) void k_split_h0(
    const float* __restrict__ hn, unsigned short* __restrict__ hi,
    unsigned short* __restrict__ lo)
{
    int gid = blockIdx.x * 256 + threadIdx.x;      // 0..32767
    int b = gid >> 7, kseg = gid & 127;
    const float* src = hn + (size_t)b * HID_ + kseg * 8;
    short8 h8, l8;
    #pragma unroll
    for (int i = 0; i < 8; ++i) {
        float v = src[i];
        unsigned short h = bf16hi(v);
        ((short*)&h8)[i] = (short)h;
        ((short*)&l8)[i] = (short)bf16hi(v - bf2f(h));
    }
    size_t off = (size_t)(kseg >> 2) * 8192 + b * 32 + (kseg & 3) * 8; // ushorts
    *(short8*)(hi + off) = h8;
    *(short8*)(lo + off) = l8;
}

// ---------------- main persistent GRU kernel (MFMA split-bf16) -------------
// R1 structure (LDS ring-3, proven 4532 us) + R4 change: corrected XOR
// bank-swizzle on the ring layout. Pitch 32 shorts (64B, 16B-aligned) with
// the 16B-slot index XORed by bits 1-2 of the row:
//   short_off = row*32 + ((seg*8) ^ (((row>>1)&3)<<3))
// slot' stays in [0,4) -> always inside the row (the R3 version used row&7
// and overflowed the row/buffer -> never shipped). Quarter-wave analysis:
// reads hit each of the 8 16B bank-groups exactly 2x (free), writes likewise.
// Same formula on staging writes, gi reads, GH_CHUNK reads -> bitwise-
// identical results to R1.
__global__ __launch_bounds__(256, 1) void k_gru(
    const float* __restrict__ input,
    const float* __restrict__ hn,
    const float* __restrict__ b_hh,
    const float* __restrict__ bc,
    const unsigned short* __restrict__ whh_hi,
    const unsigned short* __restrict__ whh_lo,
    const unsigned short* __restrict__ wc_hi,
    const unsigned short* __restrict__ wc_lo,
    unsigned short* __restrict__ hxA_hi, unsigned short* __restrict__ hxA_lo,
    unsigned short* __restrict__ hxB_hi, unsigned short* __restrict__ hxB_lo,
    float* __restrict__ hn_out,
    int* __restrict__ bar)
{
    const int g = blockIdx.x, ct = g & 31, bt = g >> 5;
    const int j0 = ct << 5, b0 = bt << 5;
    const int tid = threadIdx.x, lane = tid & 63, wid = tid >> 6;
    const int mh = wid & 1, kh = wid >> 1;
    const int l15 = lane & 15, quad = lane >> 4;

    __shared__ short smB[18432];              // 3 ring bufs x 6144 shorts
    float* smF = (float*)smB;                 // C-dump alias (post-K-loop)
    const int SIN_ = 4672, SHN_ = 6784;

    // ---- B staging descriptors: 3 x 16B segs per thread per K32 chunk ----
    const int t7 = tid & 127, pl = tid >> 7;
    const unsigned short* wsrc = pl ? whh_lo : whh_hi;
    const unsigned short* csrc = pl ? wc_lo : wc_hi;
    const char* wB[3]; const char* cB[3]; int lo_[3];
    #pragma unroll
    for (int i = 0; i < 3; ++i) {
        int sid = t7 + (i << 7);
        int n = sid >> 2, ss = sid & 3;
        int grow = (n >> 5) * HID_ + j0 + (n & 31);
        wB[i] = (const char*)wsrc + (size_t)grow * 2048u + (size_t)ss * 16u;
        cB[i] = (const char*)csrc + (size_t)grow * 128u + (size_t)ss * 16u;
        lo_[i] = (pl * 96 + n) * 32 + ((ss * 8) ^ (((n >> 1) & 3) << 3)); // swz
    }
    const int foff = l15 * 32 + ((quad * 8) ^ (((l15 >> 1) & 3) << 3));   // swz
    const size_t aoff = (size_t)((b0 + mh * 16 + l15) * 64 + quad * 16);
    const char* aAh = (const char*)hxA_hi + aoff;
    const char* aAl = (const char*)hxA_lo + aoff;
    const char* aBh = (const char*)hxB_hi + aoff;
    const char* aBl = (const char*)hxB_lo + aoff;
    const float* xrow = input + (size_t)(b0 + mh * 16 + l15) * (T_ * 64)
                              + kh * 32 + quad * 8;

    // ---- gate-phase statics: thread owns (b = b0+gb, j = j0+gj4..+3) -----
    const int gb = tid >> 3, gj4 = (tid & 7) << 2;
    float hreg[4], br[4], bz[4], bni[4], bnh[4];
    #pragma unroll
    for (int i = 0; i < 4; ++i) {
        int j = j0 + gj4 + i;
        hreg[i] = hn[(size_t)(b0 + gb) * HID_ + j];
        br[i]  = bc[j] + b_hh[j];
        bz[i]  = bc[1024 + j] + b_hh[1024 + j];
        bni[i] = bc[2048 + j];
        bnh[i] = b_hh[2048 + j];
    }
    const size_t hoff = (size_t)(ct * 16384 + (b0 + gb) * 64 + gj4 * 2);
    char* sAh = (char*)hxA_hi + hoff; char* sAl = (char*)hxA_lo + hoff;
    char* sBh = (char*)hxB_hi + hoff; char* sBl = (char*)hxB_lo + hoff;
    const int g73 = gb * 73, g33 = gb * 33;

    int* arrive  = bar + bt * 128;
    int* release = bar + bt * 128 + 32;

    short8 bp[2][3];   // weight payload, set = chunk&1
    short8 ab[2][2];   // A-frag banks [bank][hi/lo]
    f32x4 acc[6], acci[2];

#define GH_CHUNK(RB, AH, AL)                                                  \
  { _Pragma("unroll")                                                         \
    for (int nt = 0; nt < 6; ++nt) {                                          \
        short8 bh_ = *(const short8*)(smB + (RB) + nt * 512 + foff);          \
        short8 bl_ = *(const short8*)(smB + (RB) + 3072 + nt * 512 + foff);   \
        f32x4 v_ = mfma_(AH, bh_, acc[nt]);                                   \
        v_ = mfma_(AH, bl_, v_);                                              \
        v_ = mfma_(AL, bh_, v_);                                              \
        acc[nt] = v_; } }

    #pragma unroll 1
    for (int t = 0; t < 256; ++t) {
        const char* rh = (t & 1) ? aBh : aAh;   // read planes (h in)
        const char* rl = (t & 1) ? aBl : aAl;
        char* wh = (t & 1) ? sAh : sBh;         // write planes (h out)
        char* wl = (t & 1) ? sAl : sBl;

        // ---- gi staging (h-independent; overlaps the coming spin) ----
        short8 gp[2][3];
        #pragma unroll
        for (int c = 0; c < 2; ++c)
            #pragma unroll
            for (int i = 0; i < 3; ++i)
                gl16(gp[c][i], cB[i] + c * 64);
        // x_t load + split (plain cached loads; compiler-managed waits)
        float xv[8];
        *(float4*)&xv[0] = *(const float4*)(xrow + (size_t)t * 64);
        *(float4*)&xv[4] = *(const float4*)(xrow + (size_t)t * 64 + 4);
        short8 xa_hi, xa_lo;
        #pragma unroll
        for (int i = 0; i < 8; ++i) {
            unsigned short h = bf16hi(xv[i]);
            ((short*)&xa_hi)[i] = (short)h;
            ((short*)&xa_lo)[i] = (short)bf16hi(xv[i] - bf2f(h));
        }
        WAITV0();
        #pragma unroll
        for (int c = 0; c < 2; ++c)
            #pragma unroll
            for (int i = 0; i < 3; ++i)
                *(short8*)(smB + c * 6144 + lo_[i]) = gp[c][i];
        // issue w_hh chunks 0,1 (pre-spin is safe: weights are step-invariant)
        #pragma unroll
        for (int c = 0; c < 2; ++c)
            #pragma unroll
            for (int i = 0; i < 3; ++i)
                gl16(bp[c][i], wB[i] + c * 64);
        ABAR();
        // ---- gi compute (Wc chunk = kh), inits accumulators ----
        {
            const int rb = kh * 6144;
            #pragma unroll
            for (int nt = 0; nt < 6; ++nt) {
                short8 bh_ = *(const short8*)(smB + rb + nt * 512 + foff);
                short8 bl_ = *(const short8*)(smB + rb + 3072 + nt * 512 + foff);
                f32x4 z = {0.f, 0.f, 0.f, 0.f};
                f32x4 v = mfma_(xa_hi, bh_, z);
                v = mfma_(xa_hi, bl_, v);
                v = mfma_(xa_lo, bh_, v);
                if (nt < 4) { acc[nt] = v; }
                else { acci[nt - 4] = v; acc[nt] = z; }
            }
        }
        // ---- wait for h(t) published ----
        if (t > 0 && tid == 0) {
            while (__hip_atomic_load(release, __ATOMIC_RELAXED,
                                     __HIP_MEMORY_SCOPE_SYSTEM) < t)
                __builtin_amdgcn_s_sleep(4);
        }
        ABAR();
        // ---- prologue: A(chunk kh) into bank1; stage w chunk 0 -> buf 2 ----
        gl16c(ab[1][0], rh + (size_t)kh * 16384);
        gl16c(ab[1][1], rl + (size_t)kh * 16384);
        WAITV2();
        #pragma unroll
        for (int i = 0; i < 3; ++i)
            *(short8*)(smB + 12288 + lo_[i]) = bp[0][i];
        // ---- gh pipeline: ring-3, loads 2 chunks deep across barriers ----
        #pragma unroll
        for (int c = 2; c <= 31; ++c) {
            const int sN  = c & 1;
            const int bkC = (c >> 1) & 1;
            const int bkN = ((c + 1) >> 1) & 1;
            const int wofs = ((c + 1) % 3) * 6144;
            const int rofs = (c % 3) * 6144;
            if ((c & 1) == kh) {
                #pragma unroll
                for (int i = 0; i < 3; ++i)
                    gl16(bp[sN][i], wB[i] + c * 64);
                gl16c(ab[bkC ^ 1][0], rh + (size_t)c * 16384);
                gl16c(ab[bkC ^ 1][1], rl + (size_t)c * 16384);
                WAITV5_TIE(ab[bkC][0], ab[bkC][1]);
            } else {
                #pragma unroll
                for (int i = 0; i < 3; ++i)
                    gl16(bp[sN][i], wB[i] + c * 64);
                WAITV5_TIE(ab[bkN][0], ab[bkN][1]);
            }
            #pragma unroll
            for (int i = 0; i < 3; ++i)
                *(short8*)(smB + wofs + lo_[i]) = bp[sN ^ 1][i];
            ABAR();
            if ((c & 1) == kh) GH_CHUNK(rofs, ab[bkC][0], ab[bkC][1]);
        }
        // epilogue: chunks 30 (kh=0, buf 2) / 31 (kh=1, buf 0)
        WAITV0_TIE(ab[0][0], ab[0][1]);
        #pragma unroll
        for (int i = 0; i < 3; ++i)
            *(short8*)(smB + lo_[i]) = bp[1][i];          // chunk 31 -> buf 0
        ABAR();
        if (kh == 0) GH_CHUNK(12288, ab[0][0], ab[0][1]);
        if (kh == 1) GH_CHUNK(0,     ab[0][0], ab[0][1]);
        __syncthreads();
        // ---- dump C fragments (aliased over ring bufs) ----
        {
            const int row = mh * 16 + quad * 4;
            #pragma unroll
            for (int nt = 0; nt < 4; ++nt)
                #pragma unroll
                for (int r = 0; r < 4; ++r)
                    smF[kh * 2336 + (row + r) * 73 + nt * 16 + l15] = acc[nt][r];
            #pragma unroll
            for (int jn = 0; jn < 2; ++jn)
                #pragma unroll
                for (int r = 0; r < 4; ++r) {
                    smF[SHN_ + kh * 1056 + (row + r) * 33 + jn * 16 + l15] = acc[4 + jn][r];
                    smF[SIN_ + kh * 1056 + (row + r) * 33 + jn * 16 + l15] = acci[jn][r];
                }
        }
        __syncthreads();
        // ---- gate phase: thread owns (gb, gj4..+3); hprev in registers ----
        unsigned short ph4[4], pl4[4];
        #pragma unroll
        for (int i = 0; i < 4; ++i) {
            int cl = gj4 + i;
            float rp = smF[g73 + cl] + smF[2336 + g73 + cl] + br[i];
            float zp = smF[g73 + 32 + cl] + smF[2336 + g73 + 32 + cl] + bz[i];
            float ip = smF[SIN_ + g33 + cl] + smF[SIN_ + 1056 + g33 + cl] + bni[i];
            float hp = smF[SHN_ + g33 + cl] + smF[SHN_ + 1056 + g33 + cl] + bnh[i];
            float rr = sigmoidf_(rp);
            float zz = sigmoidf_(zp);
            float nn = tanhf_(ip + rr * hp);
            float hv = (1.0f - zz) * nn + zz * hreg[i];
            hreg[i] = hv;
            unsigned short hh = bf16hi(hv);
            ph4[i] = hh;
            pl4[i] = bf16hi(hv - bf2f(hh));
        }
        unsigned long long pk_hi =
            (unsigned long long)ph4[0] | ((unsigned long long)ph4[1] << 16) |
            ((unsigned long long)ph4[2] << 32) | ((unsigned long long)ph4[3] << 48);
        unsigned long long pk_lo =
            (unsigned long long)pl4[0] | ((unsigned long long)pl4[1] << 16) |
            ((unsigned long long)pl4[2] << 32) | ((unsigned long long)pl4[3] << 48);
        gs8c(wh, pk_hi);
        gs8c(wl, pk_lo);
        if (t == 255) {
            #pragma unroll
            for (int i = 0; i < 4; ++i)
                hn_out[(size_t)(b0 + gb) * HID_ + j0 + gj4 + i] = hreg[i];
        }
        WAITV0();           // h-plane stores at coherence point
        __syncthreads();    // whole block done
        if (t < 255 && tid == 0) {
            int old = __hip_atomic_fetch_add(arrive, 1, __ATOMIC_RELAXED,
                                             __HIP_MEMORY_SCOPE_SYSTEM);
            if (old == ((t + 1) << 5) - 1)
                __hip_atomic_store(release, t + 1, __ATOMIC_RELAXED,
                                   __HIP_MEMORY_SCOPE_SYSTEM);
        }
    }
#undef GH_CHUNK
}

// ---------------- fc3: out3 = relu(relu(h) @ fc3_wT + fc3_b) --------------
__global__ __launch_bounds__(256) void k_fc3(
    const float* __restrict__ h, const float* __restrict__ fc3_w,
    const float* __restrict__ fc3_b, float* __restrict__ out3)
{
    const int bt = blockIdx.x >> 3;
    const int dt = blockIdx.x & 7;
    const int b0 = bt << 6;
    const int d0 = dt << 6;
    const int tid = threadIdx.x;
    const int tx = tid & 15, ty = tid >> 4;

    __shared__ float sh_h[64][36];
    __shared__ float sh_w[64][36];

    float acc[4][4] = {};
    const int lr = tid >> 3;
    const int lc = (tid & 7) << 2;

    for (int kk = 0; kk < HID_; kk += 32) {
        #pragma unroll
        for (int p = 0; p < 2; ++p) {
            int row = lr + (p << 5);
            float4 v = *(const float4*)(h + (size_t)(b0 + row) * HID_ + kk + lc);
            v.x = fmaxf(v.x, 0.f); v.y = fmaxf(v.y, 0.f);
            v.z = fmaxf(v.z, 0.f); v.w = fmaxf(v.w, 0.f);
            *(float4*)&sh_h[row][lc] = v;
            *(float4*)&sh_w[row][lc] =
                *(const float4*)(fc3_w + (size_t)(d0 + row) * HID_ + kk + lc);
        }
        __syncthreads();
        #pragma unroll
        for (int k = 0; k < 32; ++k) {
            float hv[4], wv[4];
            #pragma unroll
            for (int i = 0; i < 4; ++i) hv[i] = sh_h[ty + (i << 4)][k];
            #pragma unroll
            for (int q = 0; q < 4; ++q) wv[q] = sh_w[tx + (q << 4)][k];
            #pragma unroll
            for (int i = 0; i < 4; ++i)
                #pragma unroll
                for (int q = 0; q < 4; ++q)
                    acc[i][q] += hv[i] * wv[q];
        }
        __syncthreads();
    }
    #pragma unroll
    for (int i = 0; i < 4; ++i) {
        int b = b0 + ty + (i << 4);
        #pragma unroll
        for (int q = 0; q < 4; ++q) {
            int d = d0 + tx + (q << 4);
            out3[(size_t)b * D2 + d] = fmaxf(acc[i][q] + fc3_b[d], 0.f);
        }
    }
}

// ---------------- heads: params[b,o] = out3[b,:]·heads_w[cid[b],o,:]+b ----
__global__ __launch_bounds__(256) void k_heads(
    const float* __restrict__ out3, const int* __restrict__ cult,
    const float* __restrict__ hw, const float* __restrict__ hb,
    float* __restrict__ params)
{
    int b = blockIdx.x;
    int o = threadIdx.x >> 4;
    int l = threadIdx.x & 15;
    int cid = cult[b];
    const float* w = hw + ((size_t)cid * 16 + o) * D2;
    const float* x = out3 + (size_t)b * D2;
    float acc = 0.f;
    #pragma unroll
    for (int m = 0; m < 8; ++m) {
        int d4 = (l + (m << 4)) << 2;
        float4 xv = *(const float4*)(x + d4);
        float4 wv = *(const float4*)(w + d4);
        acc += xv.x * wv.x + xv.y * wv.y + xv.z * wv.z + xv.w * wv.w;
    }
    #pragma unroll
    for (int s = 1; s < 16; s <<= 1)
        acc += __shfl_xor(acc, s, 16);
    if (l == 0)
        params[(size_t)b * 16 + o] = acc + hb[(size_t)cid * 16 + o];
}

extern "C" void kernel_launch(void* const* d_in, const int* in_sizes, int n_in,
                              void* d_out, int out_size, void* d_ws, size_t ws_size,
                              hipStream_t stream)
{
    const float* input = (const float*)d_in[0];
    const float* hn    = (const float*)d_in[1];
    const int*   cult  = (const int*)d_in[2];
    const float* fc1_w = (const float*)d_in[3];
    const float* fc1_b = (const float*)d_in[4];
    const float* fc2_w = (const float*)d_in[5];
    const float* fc2_b = (const float*)d_in[6];
    const float* w_ih  = (const float*)d_in[7];
    const float* w_hh  = (const float*)d_in[8];
    const float* b_ih  = (const float*)d_in[9];
    const float* b_hh  = (const float*)d_in[10];
    const float* fc3_w = (const float*)d_in[11];
    const float* fc3_b = (const float*)d_in[12];
    const float* hw    = (const float*)d_in[13];
    const float* hb    = (const float*)d_in[14];
    float* out = (float*)d_out;
    float* hn_out = out + 4096;          // params 256*16, then hn 256*1024

    char* ws = (char*)d_ws;
    int*   bar    = (int*)ws;                                   // 4 KB
    float* W2     = (float*)(ws + 4096);                        // 256 KB
    float* b2     = (float*)(ws + 266240);
    float* bc     = (float*)(ws + 270336);
    unsigned short* whh_hi = (unsigned short*)(ws + 282624);    // 6 MB
    unsigned short* whh_lo = (unsigned short*)(ws + 282624 + 6291456);
    unsigned short* wc_hi  = (unsigned short*)(ws + 12865536);
    unsigned short* wc_lo  = (unsigned short*)(ws + 13258752);
    unsigned short* hxA_hi = (unsigned short*)(ws + 13651968);
    unsigned short* hxA_lo = (unsigned short*)(ws + 14176256);
    unsigned short* hxB_hi = (unsigned short*)(ws + 14700544);
    unsigned short* hxB_lo = (unsigned short*)(ws + 15224832);
    float* out3   = (float*)(ws + 15749120);                    // 512 KB

    hipMemsetAsync(bar, 0, 4096, stream);
    k_w2<<<256, 256, 0, stream>>>(fc2_w, fc1_w, fc1_b, fc2_b, W2, b2);
    k_wc<<<768, 256, 0, stream>>>(w_ih, W2, b2, b_ih, wc_hi, wc_lo, bc);
    k_splitw<<<3072, 256, 0, stream>>>(w_hh, whh_hi, whh_lo);
    k_split_h0<<<128, 256, 0, stream>>>(hn, hxA_hi, hxA_lo);
    k_gru<<<256, 256, 0, stream>>>(input, hn, b_hh, bc,
                                   whh_hi, whh_lo, wc_hi, wc_lo,
                                   hxA_hi, hxA_lo, hxB_hi, hxB_lo,
                                   hn_out, bar);
    k_fc3<<<32, 256, 0, stream>>>(hn_out, fc3_w, fc3_b, out3);
    k_heads<<<256, 256, 0, stream>>>(out3, cult, hw, hb, out);
}

// Round 6
// 3136.534 us; speedup vs baseline: 2.0784x; 1.4069x over previous
//
#include <hip/hip_runtime.h>

#define T_   256
#define HID_ 1024
#define D2   512

typedef __attribute__((ext_vector_type(8))) short  short8;
typedef __attribute__((ext_vector_type(8))) __bf16 bf16x8;
typedef __attribute__((ext_vector_type(4))) float  f32x4;

__device__ __forceinline__ float sigmoidf_(float x) {
    return __fdividef(1.0f, 1.0f + __expf(-x));
}
__device__ __forceinline__ float tanhf_(float x) {
    return 1.0f - __fdividef(2.0f, 1.0f + __expf(2.0f * x));
}
__device__ __forceinline__ unsigned short bf16hi(float x) {
    unsigned u = __float_as_uint(x);
    return (unsigned short)((u + 0x7FFFu + ((u >> 16) & 1u)) >> 16);
}
__device__ __forceinline__ float bf2f(unsigned short h) {
    return __uint_as_float((unsigned)h << 16);
}
__device__ __forceinline__ f32x4 mfma_(short8 a, short8 b, f32x4 c) {
    union { short8 s; bf16x8 b; } ua, ub;
    ua.s = a; ub.s = b;
    return __builtin_amdgcn_mfma_f32_16x16x32_bf16(ua.b, ub.b, c, 0, 0, 0);
}

// ---- raw asm memory ops (64-bit VGPR address form: works for divergent ptrs)
__device__ __forceinline__ void gl16(short8& d, const void* p) {
    asm volatile("global_load_dwordx4 %0, %1, off" : "=v"(d) : "v"(p));
}
__device__ __forceinline__ void gl16c(short8& d, const void* p) {
    asm volatile("global_load_dwordx4 %0, %1, off sc0 sc1" : "=v"(d) : "v"(p));
}
__device__ __forceinline__ void gs8c(void* p, unsigned long long v) {
    asm volatile("global_store_dwordx2 %0, %1, off sc0 sc1"
                 :: "v"(p), "v"(v) : "memory");
}
#define WAITV0() asm volatile("s_waitcnt vmcnt(0)" ::: "memory")
#define WAITV8() asm volatile("s_waitcnt vmcnt(8)" ::: "memory")
// ties "materialize" the A-frag regs so MFMAs can't be hoisted above the wait
#define WAITV10_TIE(H, L) asm volatile("s_waitcnt vmcnt(10)" : "+v"(H), "+v"(L) :: "memory")
#define WAITV2_TIE(H, L)  asm volatile("s_waitcnt vmcnt(2)"  : "+v"(H), "+v"(L) :: "memory")
#define WAITV0_TIE(H, L)  asm volatile("s_waitcnt vmcnt(0)"  : "+v"(H), "+v"(L) :: "memory")
#define ABAR() asm volatile("s_waitcnt lgkmcnt(0)\n\ts_barrier" ::: "memory")

// ---------------- prelim: W2 = fc2_w @ fc1_w, b2 = fc2_w@fc1_b + fc2_b ----
__global__ __launch_bounds__(256) void k_w2(
    const float* __restrict__ fc2_w, const float* __restrict__ fc1_w,
    const float* __restrict__ fc1_b, const float* __restrict__ fc2_b,
    float* __restrict__ W2, float* __restrict__ b2)
{
    int idx = blockIdx.x * 256 + threadIdx.x;   // 0..65535
    int r = idx >> 6, c = idx & 63;
    float acc = 0.f;
    for (int k = 0; k < D2; ++k)
        acc += fc2_w[(size_t)r * D2 + k] * fc1_w[(size_t)k * 64 + c];
    W2[idx] = acc;
    if (c == 0) {
        float a = fc2_b[r];
        for (int k = 0; k < D2; ++k)
            a += fc2_w[(size_t)r * D2 + k] * fc1_b[k];
        b2[r] = a;
    }
}

// -------- prelim: Wc = w_ih @ W2 (bf16 split planes), bc = w_ih@b2 + b_ih --
__global__ __launch_bounds__(256) void k_wc(
    const float* __restrict__ w_ih, const float* __restrict__ W2,
    const float* __restrict__ b2, const float* __restrict__ b_ih,
    unsigned short* __restrict__ wc_hi, unsigned short* __restrict__ wc_lo,
    float* __restrict__ bc)
{
    int idx = blockIdx.x * 256 + threadIdx.x;   // 0..196607
    int r = idx >> 6, c = idx & 63;
    float acc = 0.f;
    for (int k = 0; k < HID_; ++k)
        acc += w_ih[(size_t)r * HID_ + k] * W2[(size_t)k * 64 + c];
    unsigned short h = bf16hi(acc);
    wc_hi[idx] = h;
    wc_lo[idx] = bf16hi(acc - bf2f(h));
    if (c == 0) {
        float a = b_ih[r];
        for (int k = 0; k < HID_; ++k)
            a += w_ih[(size_t)r * HID_ + k] * b2[k];
        bc[r] = a;
    }
}

// ---------------- prelim: split w_hh into bf16 hi/lo planes ----------------
__global__ __launch_bounds__(256) void k_splitw(
    const float* __restrict__ w, unsigned short* __restrict__ hi,
    unsigned short* __restrict__ lo)
{
    int i4 = (blockIdx.x * 256 + threadIdx.x) * 4;
    float4 v = *(const float4*)(w + i4);
    float vv[4] = {v.x, v.y, v.z, v.w};
    unsigned short h4[4], l4[4];
    #pragma unroll
    for (int i = 0; i < 4; ++i) {
        h4[i] = bf16hi(vv[i]);
        l4[i] = bf16hi(vv[i] - bf2f(h4[i]));
    }
    *(unsigned long long*)(hi + i4) =
        (unsigned long long)h4[0] | ((unsigned long long)h4[1] << 16) |
        ((unsigned long long)h4[2] << 32) | ((unsigned long long)h4[3] << 48);
    *(unsigned long long*)(lo + i4) =
        (unsigned long long)l4[0] | ((unsigned long long)l4[1] << 16) |
        ((unsigned long long)l4[2] << 32) | ((unsigned long long)l4[3] << 48);
}

// ------- prelim: h0 -> bf16 split planes in fragment-granule layout --------
// layout: byte = (k>>5)*16384 + b*64 + ((k>>3)&3)*16 + (k&7)*2
__global__ __launch_bounds__(256) void k_split_h0(
    const float* __restrict__ hn, unsigned short* __restrict__ hi,
    unsigned short* __restrict__ lo)
{
    int gid = blockIdx.x * 256 + threadIdx.x;      // 0..32767
    int b = gid >> 7, kseg = gid & 127;
    const float* src = hn + (size_t)b * HID_ + kseg * 8;
    short8 h8, l8;
    #pragma unroll
    for (int i = 0; i < 8; ++i) {
        float v = src[i];
        unsigned short h = bf16hi(v);
        ((short*)&h8)[i] = (short)h;
        ((short*)&l8)[i] = (short)bf16hi(v - bf2f(h));
    }
    size_t off = (size_t)(kseg >> 2) * 8192 + b * 32 + (kseg & 3) * 8; // ushorts
    *(short8*)(hi + off) = h8;
    *(short8*)(lo + off) = l8;
}

// ---------------- main persistent GRU kernel (MFMA split-bf16) -------------
// R5 change (on the R4 skeleton + swizzle): K-loop processes K=64 GRANULES
// (2 K32 chunks) per barrier interval -> 15 ABARs instead of 30. Ring-3 of
// 12288-short bufs; granule G lives in buf G%3 (chunk-local layout identical
// to R4's 6144-short chunk regions, so the swizzled lo_/foff formulas are
// unchanged). Both kh-waves compute EVERY interval: wave kh takes chunk
// 2G+kh of granule G -> same per-wave chunk set/order as R4 => bitwise-
// identical output, and symmetric per-wave work (no alternating barrier
// skew). vmcnt ledger (per wave; oldest-first queue):
//   pre-spin: issue W0(6),W1(6); post-spin: issue A0(2); vmcnt(8) forces W0;
//   write W0->buf0; issue A1(2); ABAR.
//   iter G<=13: issue W(G+2)(6), A(G+2)(2); vmcnt(10) forces exactly
//     {W(G+1), A(G)} (A flies ~2 intervals -> covers L3 latency);
//     write W(G+1)->buf (G+1)%3; ABAR; compute granule G from buf G%3.
//   G=14: vmcnt(2); G=15: vmcnt(0). A banks 3-deep (G%3), W sets 2-deep.
__global__ __launch_bounds__(256, 1) void k_gru(
    const float* __restrict__ input,
    const float* __restrict__ hn,
    const float* __restrict__ b_hh,
    const float* __restrict__ bc,
    const unsigned short* __restrict__ whh_hi,
    const unsigned short* __restrict__ whh_lo,
    const unsigned short* __restrict__ wc_hi,
    const unsigned short* __restrict__ wc_lo,
    unsigned short* __restrict__ hxA_hi, unsigned short* __restrict__ hxA_lo,
    unsigned short* __restrict__ hxB_hi, unsigned short* __restrict__ hxB_lo,
    float* __restrict__ hn_out,
    int* __restrict__ bar)
{
    const int g = blockIdx.x, ct = g & 31, bt = g >> 5;
    const int j0 = ct << 5, b0 = bt << 5;
    const int tid = threadIdx.x, lane = tid & 63, wid = tid >> 6;
    const int mh = wid & 1, kh = wid >> 1;
    const int l15 = lane & 15, quad = lane >> 4;

    __shared__ short smB[36864];              // 3 ring bufs x 12288 shorts
    float* smF = (float*)smB;                 // C-dump alias (post-K-loop)
    const int SIN_ = 4672, SHN_ = 6784;

    // ---- B staging descriptors: 3 x 16B segs per thread per K32 chunk ----
    const int t7 = tid & 127, pl = tid >> 7;
    const unsigned short* wsrc = pl ? whh_lo : whh_hi;
    const unsigned short* csrc = pl ? wc_lo : wc_hi;
    const char* wB[3]; const char* cB[3]; int lo_[3];
    #pragma unroll
    for (int i = 0; i < 3; ++i) {
        int sid = t7 + (i << 7);
        int n = sid >> 2, ss = sid & 3;
        int grow = (n >> 5) * HID_ + j0 + (n & 31);
        wB[i] = (const char*)wsrc + (size_t)grow * 2048u + (size_t)ss * 16u;
        cB[i] = (const char*)csrc + (size_t)grow * 128u + (size_t)ss * 16u;
        lo_[i] = (pl * 96 + n) * 32 + ((ss * 8) ^ (((n >> 1) & 3) << 3)); // swz
    }
    const int foff = l15 * 32 + ((quad * 8) ^ (((l15 >> 1) & 3) << 3));   // swz
    const size_t aoff = (size_t)((b0 + mh * 16 + l15) * 64 + quad * 16);
    const char* aAh = (const char*)hxA_hi + aoff;
    const char* aAl = (const char*)hxA_lo + aoff;
    const char* aBh = (const char*)hxB_hi + aoff;
    const char* aBl = (const char*)hxB_lo + aoff;
    const float* xrow = input + (size_t)(b0 + mh * 16 + l15) * (T_ * 64)
                              + kh * 32 + quad * 8;

    // ---- gate-phase statics: thread owns (b = b0+gb, j = j0+gj4..+3) -----
    const int gb = tid >> 3, gj4 = (tid & 7) << 2;
    float hreg[4], br[4], bz[4], bni[4], bnh[4];
    #pragma unroll
    for (int i = 0; i < 4; ++i) {
        int j = j0 + gj4 + i;
        hreg[i] = hn[(size_t)(b0 + gb) * HID_ + j];
        br[i]  = bc[j] + b_hh[j];
        bz[i]  = bc[1024 + j] + b_hh[1024 + j];
        bni[i] = bc[2048 + j];
        bnh[i] = b_hh[2048 + j];
    }
    const size_t hoff = (size_t)(ct * 16384 + (b0 + gb) * 64 + gj4 * 2);
    char* sAh = (char*)hxA_hi + hoff; char* sAl = (char*)hxA_lo + hoff;
    char* sBh = (char*)hxB_hi + hoff; char* sBl = (char*)hxB_lo + hoff;
    const int g73 = gb * 73, g33 = gb * 33;

    int* arrive  = bar + bt * 128;
    int* release = bar + bt * 128 + 32;

    short8 bp[2][6];   // weight payload for a K64 granule, set = granule&1
    short8 ab[3][2];   // A-frag banks [granule%3][hi/lo]
    f32x4 acc[6], acci[2];

#define GH_CHUNK(RB, AH, AL)                                                  \
  { _Pragma("unroll")                                                         \
    for (int nt = 0; nt < 6; ++nt) {                                          \
        short8 bh_ = *(const short8*)(smB + (RB) + nt * 512 + foff);          \
        short8 bl_ = *(const short8*)(smB + (RB) + 3072 + nt * 512 + foff);   \
        f32x4 v_ = mfma_(AH, bh_, acc[nt]);                                   \
        v_ = mfma_(AH, bl_, v_);                                              \
        v_ = mfma_(AL, bh_, v_);                                              \
        acc[nt] = v_; } }

    #pragma unroll 1
    for (int t = 0; t < 256; ++t) {
        const char* rh = (t & 1) ? aBh : aAh;   // read planes (h in)
        const char* rl = (t & 1) ? aBl : aAl;
        char* wh = (t & 1) ? sAh : sBh;         // write planes (h out)
        char* wl = (t & 1) ? sAl : sBl;

        // ---- gi staging (h-independent; overlaps the coming spin) ----
        short8 gp[6];
        #pragma unroll
        for (int j = 0; j < 6; ++j)
            gl16(gp[j], cB[j % 3] + (j / 3) * 64);
        // x_t load + split (plain cached loads; compiler-managed waits)
        float xv[8];
        *(float4*)&xv[0] = *(const float4*)(xrow + (size_t)t * 64);
        *(float4*)&xv[4] = *(const float4*)(xrow + (size_t)t * 64 + 4);
        short8 xa_hi, xa_lo;
        #pragma unroll
        for (int i = 0; i < 8; ++i) {
            unsigned short h = bf16hi(xv[i]);
            ((short*)&xa_hi)[i] = (short)h;
            ((short*)&xa_lo)[i] = (short)bf16hi(xv[i] - bf2f(h));
        }
        WAITV0();
        #pragma unroll
        for (int j = 0; j < 6; ++j)
            *(short8*)(smB + (j / 3) * 6144 + lo_[j % 3]) = gp[j];
        // issue w_hh granules 0 (chunks 0,1) and 1 (chunks 2,3) pre-spin
        #pragma unroll
        for (int j = 0; j < 6; ++j)
            gl16(bp[0][j], wB[j % 3] + (size_t)(j / 3) * 64);
        #pragma unroll
        for (int j = 0; j < 6; ++j)
            gl16(bp[1][j], wB[j % 3] + (size_t)(2 + j / 3) * 64);
        ABAR();
        // ---- gi compute (Wc chunk = kh), inits accumulators ----
        {
            const int rb = kh * 6144;
            #pragma unroll
            for (int nt = 0; nt < 6; ++nt) {
                short8 bh_ = *(const short8*)(smB + rb + nt * 512 + foff);
                short8 bl_ = *(const short8*)(smB + rb + 3072 + nt * 512 + foff);
                f32x4 z = {0.f, 0.f, 0.f, 0.f};
                f32x4 v = mfma_(xa_hi, bh_, z);
                v = mfma_(xa_hi, bl_, v);
                v = mfma_(xa_lo, bh_, v);
                if (nt < 4) { acc[nt] = v; }
                else { acci[nt - 4] = v; acc[nt] = z; }
            }
        }
        // ---- wait for h(t) published ----
        if (t > 0 && tid == 0) {
            while (__hip_atomic_load(release, __ATOMIC_RELAXED,
                                     __HIP_MEMORY_SCOPE_SYSTEM) < t)
                __builtin_amdgcn_s_sleep(4);
        }
        ABAR();
        // ---- prologue: A(granule 0), write W0 -> buf0, A(granule 1) ----
        gl16c(ab[0][0], rh + (size_t)kh * 16384);
        gl16c(ab[0][1], rl + (size_t)kh * 16384);
        WAITV8();
        #pragma unroll
        for (int j = 0; j < 6; ++j)
            *(short8*)(smB + (j / 3) * 6144 + lo_[j % 3]) = bp[0][j];
        gl16c(ab[1][0], rh + (size_t)(2 + kh) * 16384);
        gl16c(ab[1][1], rl + (size_t)(2 + kh) * 16384);
        ABAR();
        // ---- gh pipeline: 16 K64 granules, ring-3, 1 barrier each ----
        #pragma unroll
        for (int G = 0; G < 16; ++G) {
            if (G <= 13) {
                #pragma unroll
                for (int j = 0; j < 6; ++j)
                    gl16(bp[G & 1][j],
                         wB[j % 3] + (size_t)(2 * G + 4 + j / 3) * 64);
                gl16c(ab[(G + 2) % 3][0], rh + (size_t)(2 * (G + 2) + kh) * 16384);
                gl16c(ab[(G + 2) % 3][1], rl + (size_t)(2 * (G + 2) + kh) * 16384);
                WAITV10_TIE(ab[G % 3][0], ab[G % 3][1]);
            } else if (G == 14) {
                WAITV2_TIE(ab[2][0], ab[2][1]);
            } else {
                WAITV0_TIE(ab[0][0], ab[0][1]);
            }
            if (G <= 14) {
                #pragma unroll
                for (int j = 0; j < 6; ++j)
                    *(short8*)(smB + ((G + 1) % 3) * 12288 + (j / 3) * 6144
                               + lo_[j % 3]) = bp[(G + 1) & 1][j];
                ABAR();
            }
            GH_CHUNK((G % 3) * 12288 + kh * 6144, ab[G % 3][0], ab[G % 3][1]);
        }
        __syncthreads();
        // ---- dump C fragments (aliased over ring bufs) ----
        {
            const int row = mh * 16 + quad * 4;
            #pragma unroll
            for (int nt = 0; nt < 4; ++nt)
                #pragma unroll
                for (int r = 0; r < 4; ++r)
                    smF[kh * 2336 + (row + r) * 73 + nt * 16 + l15] = acc[nt][r];
            #pragma unroll
            for (int jn = 0; jn < 2; ++jn)
                #pragma unroll
                for (int r = 0; r < 4; ++r) {
                    smF[SHN_ + kh * 1056 + (row + r) * 33 + jn * 16 + l15] = acc[4 + jn][r];
                    smF[SIN_ + kh * 1056 + (row + r) * 33 + jn * 16 + l15] = acci[jn][r];
                }
        }
        __syncthreads();
        // ---- gate phase: thread owns (gb, gj4..+3); hprev in registers ----
        unsigned short ph4[4], pl4[4];
        #pragma unroll
        for (int i = 0; i < 4; ++i) {
            int cl = gj4 + i;
            float rp = smF[g73 + cl] + smF[2336 + g73 + cl] + br[i];
            float zp = smF[g73 + 32 + cl] + smF[2336 + g73 + 32 + cl] + bz[i];
            float ip = smF[SIN_ + g33 + cl] + smF[SIN_ + 1056 + g33 + cl] + bni[i];
            float hp = smF[SHN_ + g33 + cl] + smF[SHN_ + 1056 + g33 + cl] + bnh[i];
            float rr = sigmoidf_(rp);
            float zz = sigmoidf_(zp);
            float nn = tanhf_(ip + rr * hp);
            float hv = (1.0f - zz) * nn + zz * hreg[i];
            hreg[i] = hv;
            unsigned short hh = bf16hi(hv);
            ph4[i] = hh;
            pl4[i] = bf16hi(hv - bf2f(hh));
        }
        unsigned long long pk_hi =
            (unsigned long long)ph4[0] | ((unsigned long long)ph4[1] << 16) |
            ((unsigned long long)ph4[2] << 32) | ((unsigned long long)ph4[3] << 48);
        unsigned long long pk_lo =
            (unsigned long long)pl4[0] | ((unsigned long long)pl4[1] << 16) |
            ((unsigned long long)pl4[2] << 32) | ((unsigned long long)pl4[3] << 48);
        gs8c(wh, pk_hi);
        gs8c(wl, pk_lo);
        if (t == 255) {
            #pragma unroll
            for (int i = 0; i < 4; ++i)
                hn_out[(size_t)(b0 + gb) * HID_ + j0 + gj4 + i] = hreg[i];
        }
        WAITV0();           // h-plane stores at coherence point
        __syncthreads();    // whole block done
        if (t < 255 && tid == 0) {
            int old = __hip_atomic_fetch_add(arrive, 1, __ATOMIC_RELAXED,
                                             __HIP_MEMORY_SCOPE_SYSTEM);
            if (old == ((t + 1) << 5) - 1)
                __hip_atomic_store(release, t + 1, __ATOMIC_RELAXED,
                                   __HIP_MEMORY_SCOPE_SYSTEM);
        }
    }
#undef GH_CHUNK
}

// ---------------- fc3: out3 = relu(relu(h) @ fc3_wT + fc3_b) --------------
__global__ __launch_bounds__(256) void k_fc3(
    const float* __restrict__ h, const float* __restrict__ fc3_w,
    const float* __restrict__ fc3_b, float* __restrict__ out3)
{
    const int bt = blockIdx.x >> 3;
    const int dt = blockIdx.x & 7;
    const int b0 = bt << 6;
    const int d0 = dt << 6;
    const int tid = threadIdx.x;
    const int tx = tid & 15, ty = tid >> 4;

    __shared__ float sh_h[64][36];
    __shared__ float sh_w[64][36];

    float acc[4][4] = {};
    const int lr = tid >> 3;
    const int lc = (tid & 7) << 2;

    for (int kk = 0; kk < HID_; kk += 32) {
        #pragma unroll
        for (int p = 0; p < 2; ++p) {
            int row = lr + (p << 5);
            float4 v = *(const float4*)(h + (size_t)(b0 + row) * HID_ + kk + lc);
            v.x = fmaxf(v.x, 0.f); v.y = fmaxf(v.y, 0.f);
            v.z = fmaxf(v.z, 0.f); v.w = fmaxf(v.w, 0.f);
            *(float4*)&sh_h[row][lc] = v;
            *(float4*)&sh_w[row][lc] =
                *(const float4*)(fc3_w + (size_t)(d0 + row) * HID_ + kk + lc);
        }
        __syncthreads();
        #pragma unroll
        for (int k = 0; k < 32; ++k) {
            float hv[4], wv[4];
            #pragma unroll
            for (int i = 0; i < 4; ++i) hv[i] = sh_h[ty + (i << 4)][k];
            #pragma unroll
            for (int q = 0; q < 4; ++q) wv[q] = sh_w[tx + (q << 4)][k];
            #pragma unroll
            for (int i = 0; i < 4; ++i)
                #pragma unroll
                for (int q = 0; q < 4; ++q)
                    acc[i][q] += hv[i] * wv[q];
        }
        __syncthreads();
    }
    #pragma unroll
    for (int i = 0; i < 4; ++i) {
        int b = b0 + ty + (i << 4);
        #pragma unroll
        for (int q = 0; q < 4; ++q) {
            int d = d0 + tx + (q << 4);
            out3[(size_t)b * D2 + d] = fmaxf(acc[i][q] + fc3_b[d], 0.f);
        }
    }
}

// ---------------- heads: params[b,o] = out3[b,:]·heads_w[cid[b],o,:]+b ----
__global__ __launch_bounds__(256) void k_heads(
    const float* __restrict__ out3, const int* __restrict__ cult,
    const float* __restrict__ hw, const float* __restrict__ hb,
    float* __restrict__ params)
{
    int b = blockIdx.x;
    int o = threadIdx.x >> 4;
    int l = threadIdx.x & 15;
    int cid = cult[b];
    const float* w = hw + ((size_t)cid * 16 + o) * D2;
    const float* x = out3 + (size_t)b * D2;
    float acc = 0.f;
    #pragma unroll
    for (int m = 0; m < 8; ++m) {
        int d4 = (l + (m << 4)) << 2;
        float4 xv = *(const float4*)(x + d4);
        float4 wv = *(const float4*)(w + d4);
        acc += xv.x * wv.x + xv.y * wv.y + xv.z * wv.z + xv.w * wv.w;
    }
    #pragma unroll
    for (int s = 1; s < 16; s <<= 1)
        acc += __shfl_xor(acc, s, 16);
    if (l == 0)
        params[(size_t)b * 16 + o] = acc + hb[(size_t)cid * 16 + o];
}

extern "C" void kernel_launch(void* const* d_in, const int* in_sizes, int n_in,
                              void* d_out, int out_size, void* d_ws, size_t ws_size,
                              hipStream_t stream)
{
    const float* input = (const float*)d_in[0];
    const float* hn    = (const float*)d_in[1];
    const int*   cult  = (const int*)d_in[2];
    const float* fc1_w = (const float*)d_in[3];
    const float* fc1_b = (const float*)d_in[4];
    const float* fc2_w = (const float*)d_in[5];
    const float* fc2_b = (const float*)d_in[6];
    const float* w_ih  = (const float*)d_in[7];
    const float* w_hh  = (const float*)d_in[8];
    const float* b_ih  = (const float*)d_in[9];
    const float* b_hh  = (const float*)d_in[10];
    const float* fc3_w = (const float*)d_in[11];
    const float* fc3_b = (const float*)d_in[12];
    const float* hw    = (const float*)d_in[13];
    const float* hb    = (const float*)d_in[14];
    float* out = (float*)d_out;
    float* hn_out = out + 4096;          // params 256*16, then hn 256*1024

    char* ws = (char*)d_ws;
    int*   bar    = (int*)ws;                                   // 4 KB
    float* W2     = (float*)(ws + 4096);                        // 256 KB
    float* b2     = (float*)(ws + 266240);
    float* bc     = (float*)(ws + 270336);
    unsigned short* whh_hi = (unsigned short*)(ws + 282624);    // 6 MB
    unsigned short* whh_lo = (unsigned short*)(ws + 282624 + 6291456);
    unsigned short* wc_hi  = (unsigned short*)(ws + 12865536);
    unsigned short* wc_lo  = (unsigned short*)(ws + 13258752);
    unsigned short* hxA_hi = (unsigned short*)(ws + 13651968);
    unsigned short* hxA_lo = (unsigned short*)(ws + 14176256);
    unsigned short* hxB_hi = (unsigned short*)(ws + 14700544);
    unsigned short* hxB_lo = (unsigned short*)(ws + 15224832);
    float* out3   = (float*)(ws + 15749120);                    // 512 KB

    hipMemsetAsync(bar, 0, 4096, stream);
    k_w2<<<256, 256, 0, stream>>>(fc2_w, fc1_w, fc1_b, fc2_b, W2, b2);
    k_wc<<<768, 256, 0, stream>>>(w_ih, W2, b2, b_ih, wc_hi, wc_lo, bc);
    k_splitw<<<3072, 256, 0, stream>>>(w_hh, whh_hi, whh_lo);
    k_split_h0<<<128, 256, 0, stream>>>(hn, hxA_hi, hxA_lo);
    k_gru<<<256, 256, 0, stream>>>(input, hn, b_hh, bc,
                                   whh_hi, whh_lo, wc_hi, wc_lo,
                                   hxA_hi, hxA_lo, hxB_hi, hxB_lo,
                                   hn_out, bar);
    k_fc3<<<32, 256, 0, stream>>>(hn_out, fc3_w, fc3_b, out3);
    k_heads<<<256, 256, 0, stream>>>(out3, cult, hw, hb, out);
}